// Round 8
// baseline (654.593 us; speedup 1.0000x reference)
//
#include <hip/hip_runtime.h>

#define NN 50000
#define EE 1600000
#define HD 256
#define MPAD 50048      // 391 * 128
#define LN_EPS 1e-5f

#define NB 256          // coarse buckets
#define BR 196          // node range per bucket (256*196 = 50176)
#define NTOT (NB * BR)  // 50176
#define NBLK 128        // radix count/scatter blocks
#define CH 12500        // edges per block
#define SL 16           // src slices (src>>12, 4096 nodes = 2MB bf16 slice)
#define SSH 12
#define FB 3136         // fine bins = BR*SL
#define FBP 3328        // padded to 256*13
#define CF 13           // fine scan chunk per thread

#define NPW 13          // nodes per wave in aggregate_v3

typedef unsigned short ushort_t;
typedef unsigned int uint_t;

using frag_ab = __attribute__((ext_vector_type(8))) short;   // 8 bf16
using frag_cd = __attribute__((ext_vector_type(4))) float;   // 4 f32

__device__ __forceinline__ ushort_t f2bf(float f) {
    uint_t u = __float_as_uint(f);
    uint_t r = (u + 0x7FFFu + ((u >> 16) & 1u)) >> 16;
    return (ushort_t)r;
}
__device__ __forceinline__ float blo(uint_t u) { return __uint_as_float(u << 16); }
__device__ __forceinline__ float bhi(uint_t u) { return __uint_as_float(u & 0xFFFF0000u); }

// ============ radix pass 1: coarse counts, per-wave sub-histograms ============
__global__ __launch_bounds__(256) void radix_count(
    const int* __restrict__ src, const int* __restrict__ dst,
    int* __restrict__ cntD, int* __restrict__ cntS)
{
    __shared__ int hD[4][NB], hS[4][NB];
    int t = threadIdx.x, blk = blockIdx.x, wv = t >> 6;
    #pragma unroll
    for (int w = 0; w < 4; w++) { hD[w][t] = 0; hS[w][t] = 0; }
    __syncthreads();
    for (int i = t; i < CH; i += 256) {
        int e = blk * CH + i;
        atomicAdd(&hD[wv][dst[e] / BR], 1);
        atomicAdd(&hS[wv][src[e] / BR], 1);
    }
    __syncthreads();
    cntD[t * NBLK + blk] = hD[0][t] + hD[1][t] + hD[2][t] + hD[3][t];
    cntS[t * NBLK + blk] = hS[0][t] + hS[1][t] + hS[2][t] + hS[3][t];
}

// ============ radix scan: exclusive scan of 32768 (bucket-major) ==============
__global__ __launch_bounds__(256) void radix_scan(
    const int* __restrict__ cntD, int* __restrict__ scanD, int* __restrict__ bbD,
    const int* __restrict__ cntS, int* __restrict__ scanS, int* __restrict__ bbS)
{
    const int* cnt = (blockIdx.x == 0) ? cntD : cntS;
    int* scn       = (blockIdx.x == 0) ? scanD : scanS;
    int* bb        = (blockIdx.x == 0) ? bbD : bbS;
    int t = threadIdx.x, lane = t & 63, wv = t >> 6;
    int base = t * NBLK;
    int s = 0;
    for (int j = 0; j < NBLK; j++) s += cnt[base + j];
    int sc = s;
    #pragma unroll
    for (int off = 1; off < 64; off <<= 1) {
        int nv = __shfl_up(sc, off);
        if (lane >= off) sc += nv;
    }
    __shared__ int wp[4];
    if (lane == 63) wp[wv] = sc;
    __syncthreads();
    int wb = 0;
    for (int w = 0; w < wv; w++) wb += wp[w];
    int run = wb + sc - s;
    bb[t] = run;
    for (int j = 0; j < NBLK; j++) { scn[base + j] = run; run += cnt[base + j]; }
    if (t == 255) bb[256] = run;    // total = EE
}

// ============ radix scatter: dst-partition (packed 4B) and src-partition ======
__global__ __launch_bounds__(256) void radix_scatter(
    const int* __restrict__ src, const int* __restrict__ dst,
    const int* __restrict__ scanD, const int* __restrict__ scanS,
    uint_t* __restrict__ dpart, int* __restrict__ spart)
{
    __shared__ int curD[NB], curS[NB];
    int t = threadIdx.x, blk = blockIdx.x;
    curD[t] = scanD[t * NBLK + blk];
    curS[t] = scanS[t * NBLK + blk];
    __syncthreads();
    for (int i = t; i < CH; i += 256) {
        int e = blk * CH + i;
        int sv = src[e], dv = dst[e];
        int bk = dv / BR;
        int ld = dv - bk * BR;                 // 0..195, 8 bits
        int pd = atomicAdd(&curD[bk], 1);
        dpart[pd] = (uint_t)sv | ((uint_t)ld << 16);   // sv fits 16 bits
        int ps = atomicAdd(&curS[sv / BR], 1);
        spart[ps] = sv;
    }
}

// ============ fine stage (dst): per-bucket CSR sorted by (dst, src-slice) =====
__global__ __launch_bounds__(256) void fine_dst(
    const uint_t* __restrict__ dpart, const int* __restrict__ bbD,
    int* __restrict__ rp16, int* __restrict__ csr_src)
{
    __shared__ int hist[FBP];
    __shared__ int cur[FBP];
    __shared__ int wp[4];
    int t = threadIdx.x, lane = t & 63, wv = t >> 6;
    int b = blockIdx.x;
    int bb = bbD[b];
    int cnt = bbD[b + 1] - bb;
    #pragma unroll
    for (int j = 0; j < CF; j++) hist[t * CF + j] = 0;
    __syncthreads();
    for (int i = t; i < cnt; i += 256) {
        uint_t p = dpart[bb + i];
        int sv = (int)(p & 0xFFFFu);
        int ld = (int)(p >> 16);
        atomicAdd(&hist[ld * SL + (sv >> SSH)], 1);
    }
    __syncthreads();
    int vals[CF];
    int s = 0;
    #pragma unroll
    for (int j = 0; j < CF; j++) { vals[j] = hist[t * CF + j]; s += vals[j]; }
    int sc = s;
    #pragma unroll
    for (int off = 1; off < 64; off <<= 1) {
        int nv = __shfl_up(sc, off);
        if (lane >= off) sc += nv;
    }
    if (lane == 63) wp[wv] = sc;
    __syncthreads();
    int wb = 0;
    for (int w = 0; w < wv; w++) wb += wp[w];
    int run = wb + sc - s;
    #pragma unroll
    for (int j = 0; j < CF; j++) {
        int bin = t * CF + j;
        cur[bin] = run;
        if (bin < FB) rp16[b * FB + bin] = bb + run;
        run += vals[j];
    }
    if (b == NB - 1 && t == 0) rp16[NB * FB] = bbD[NB];   // sentinel = EE
    __syncthreads();
    for (int i = t; i < cnt; i += 256) {
        uint_t p = dpart[bb + i];
        int sv = (int)(p & 0xFFFFu);
        int ld = (int)(p >> 16);
        int pos = bb + atomicAdd(&cur[ld * SL + (sv >> SSH)], 1);
        csr_src[pos] = sv;
    }
}

// ============ fine stage (src): per-bucket histogram -> deg_out ===============
__global__ __launch_bounds__(256) void fine_src(
    const int* __restrict__ spart, const int* __restrict__ bbS,
    int* __restrict__ deg_out)
{
    __shared__ int hist[NB];
    int t = threadIdx.x, b = blockIdx.x;
    hist[t] = 0;
    __syncthreads();
    int bb = bbS[b];
    int cnt = bbS[b + 1] - bb;
    int node0 = b * BR;
    for (int i = t; i < cnt; i += 256) atomicAdd(&hist[spart[bb + i] - node0], 1);
    __syncthreads();
    if (t < BR) deg_out[node0 + t] = hist[t];
}

// ---------------- W convert + transpose (both weights, one launch) ------------
__global__ void wconv2(const float* __restrict__ W1, const float* __restrict__ W2,
                       ushort_t* __restrict__ Wt1, ushort_t* __restrict__ Wt2) {
    int b = blockIdx.x;
    const float* W = (b < 256) ? W1 : W2;
    ushort_t* Wt   = (b < 256) ? Wt1 : Wt2;
    int g = (b & 255) * 256 + threadIdx.x;
    int k = g >> 8, n = g & 255;
    Wt[n * 256 + k] = f2bf(W[g]);
}

// ---------------- bf16 MFMA GEMM: BM=64, BN=256 (one pass over A) -------------
__device__ __forceinline__ int swz(int r, int kElem) {
    return ((r * 64 + kElem) * 2) ^ ((r & 7) << 4);
}

template <int A_BF16>
__global__ __launch_bounds__(256) void gemm_mfma(
    const void* __restrict__ Aptr, const ushort_t* __restrict__ Wt,
    const int* __restrict__ deg, ushort_t* __restrict__ Y)
{
    __shared__ __align__(16) ushort_t As[4096];    // 64 rows x 64 k (swizzled)
    __shared__ __align__(16) ushort_t Bs[16384];   // 256 cols x 64 k (swizzled)
    __shared__ float sS[64];

    int t = threadIdx.x;
    int lane = t & 63, wn = t >> 6;     // 4 waves, each owns 64x64 output
    int row0 = blockIdx.x * 64;

    if (t < 64) {
        int row = row0 + t;
        int dg = (row < NN) ? deg[row] : 1;
        sS[t] = rsqrtf((float)(dg > 1 ? dg : 1));
    }

    frag_cd acc[4][4];
    #pragma unroll
    for (int m = 0; m < 4; m++)
        #pragma unroll
        for (int n = 0; n < 4; n++) acc[m][n] = (frag_cd)(0.f);

    const float*    Af = (const float*)Aptr;
    const ushort_t* Ab = (const ushort_t*)Aptr;

    for (int k0 = 0; k0 < HD; k0 += 64) {
        __syncthreads();
        // stage A: 64x64 (4 iters)
        #pragma unroll
        for (int i = 0; i < 4; i++) {
            int flat = i * 256 + t;
            int r = flat >> 4;
            int k4 = (flat & 15) * 4;
            int row = row0 + r;
            ushort4 u;
            if constexpr (!A_BF16) {
                float4 v = make_float4(0.f, 0.f, 0.f, 0.f);
                if (row < NN) v = *(const float4*)&Af[(size_t)row * 256 + k0 + k4];
                u.x = f2bf(v.x); u.y = f2bf(v.y); u.z = f2bf(v.z); u.w = f2bf(v.w);
            } else {
                if (row < NN) u = *(const ushort4*)&Ab[(size_t)row * 256 + k0 + k4];
                else u = make_ushort4(0, 0, 0, 0);
            }
            *(ushort4*)((char*)As + swz(r, k4)) = u;
        }
        // stage B: 256x64 (16 iters) — Wt is L2-resident (128 KB)
        #pragma unroll
        for (int i = 0; i < 16; i++) {
            int flat = i * 256 + t;
            int nn = flat >> 4;
            int k4 = (flat & 15) * 4;
            ushort4 u = *(const ushort4*)&Wt[(size_t)nn * 256 + k0 + k4];
            *(ushort4*)((char*)Bs + swz(nn, k4)) = u;
        }
        __syncthreads();
        #pragma unroll
        for (int s = 0; s < 2; s++) {
            int kb = s * 32 + ((lane >> 4) * 8);
            frag_ab af[4], bfr[4];
            #pragma unroll
            for (int m = 0; m < 4; m++) {
                int r = m * 16 + (lane & 15);
                af[m] = *(const frag_ab*)((const char*)As + swz(r, kb));
            }
            #pragma unroll
            for (int n = 0; n < 4; n++) {
                int c = wn * 64 + n * 16 + (lane & 15);
                bfr[n] = *(const frag_ab*)((const char*)Bs + swz(c, kb));
            }
            #pragma unroll
            for (int m = 0; m < 4; m++)
                #pragma unroll
                for (int n = 0; n < 4; n++)
                    acc[m][n] = __builtin_amdgcn_mfma_f32_16x16x32_bf16(
                        af[m], bfr[n], acc[m][n], 0, 0, 0);
        }
    }

    #pragma unroll
    for (int m = 0; m < 4; m++) {
        int rl = m * 16 + ((lane >> 4) * 4);
        #pragma unroll
        for (int j = 0; j < 4; j++) {
            float sc = sS[rl + j];
            size_t grow = (size_t)(row0 + rl + j);
            #pragma unroll
            for (int n = 0; n < 4; n++) {
                int gcol = wn * 64 + n * 16 + (lane & 15);
                Y[grow * 256 + gcol] = f2bf(acc[m][n][j] * sc);
            }
        }
    }
}

// ---------------- phased-v3 aggregation: slice-outer, q-outer/j-inner --------
// 965 co-resident blocks (4/CU); wave owns NPW consecutive nodes. Within a
// slice, iterate edge-position q outer and node j inner: up to NPW independent
// gathers issued back-to-back (wave-uniform predicates, no divergence).
template <int MODE>
__global__ __launch_bounds__(256, 4) void aggregate_v3(
    const ushort_t* __restrict__ msg, const int* __restrict__ rp16,
    const int* __restrict__ csr_src,
    const float* __restrict__ bias, const float* __restrict__ gamma,
    const float* __restrict__ beta, void* __restrict__ outp)
{
    int lane = threadIdx.x & 63;
    int gw = blockIdx.x * 4 + (threadIdx.x >> 6);
    int n0 = gw * NPW;
    if (n0 >= NTOT) return;
    int nv = NTOT - n0; if (nv > NPW) nv = NPW;

    int li = lane & 31;
    int li2 = (li < nv) ? li : 0;
    int hi = (lane >= 32) ? 1 : 0;

    int start_lane = rp16[(n0 + li2) * SL];
    int end_lane   = rp16[(n0 + li2) * SL + SL];

    // preload up to 64 edge indices per node (lane i holds index i)
    int ss[NPW];
    #pragma unroll
    for (int j = 0; j < NPW; j++) {
        int sj = __shfl(start_lane, j);
        int ej = __shfl(end_lane, j);
        int c  = ej - sj; if (c > 64) c = 64; if (c < 1) c = 1;
        ss[j] = csr_src[sj + ((lane < c) ? lane : 0)];
    }

    float a[NPW][4];
    #pragma unroll
    for (int j = 0; j < NPW; j++) { a[j][0] = a[j][1] = a[j][2] = a[j][3] = 0.f; }
    const uint2* base = (const uint2*)msg;

    for (int s = 0; s < SL; s++) {
        int bnd = rp16[(n0 + li2) * SL + s + hi];
        int ql[NPW];      // packed: q0 | len<<8  (both <= 64)
        int qmax = 0;
        #pragma unroll
        for (int j = 0; j < NPW; j++) {
            if (j < nv) {
                int e0 = __shfl(bnd, j);
                int e1 = __shfl(bnd, 32 + j);
                int sj = __shfl(start_lane, j);
                int u0 = e0 - sj; if (u0 > 64) u0 = 64;
                int u1 = e1 - sj; if (u1 > 64) u1 = 64;
                int len = u1 - u0;
                ql[j] = u0 | (len << 8);
                if (len > qmax) qmax = len;
            } else ql[j] = 0;
        }
        for (int q = 0; q < qmax; q++) {
            uint2 v[NPW];
            #pragma unroll
            for (int j = 0; j < NPW; j++) {
                if (q < (ql[j] >> 8)) {
                    int idx = __shfl(ss[j], (ql[j] & 0xFF) + q);
                    v[j] = base[(size_t)idx * 64 + lane];
                }
            }
            #pragma unroll
            for (int j = 0; j < NPW; j++) {
                if (q < (ql[j] >> 8)) {
                    a[j][0] += blo(v[j].x); a[j][1] += bhi(v[j].x);
                    a[j][2] += blo(v[j].y); a[j][3] += bhi(v[j].y);
                }
            }
        }
    }

    // rare tail: deg > 64 (beyond the preloaded window)
    #pragma unroll
    for (int j = 0; j < NPW; j++) {
        if (j < nv) {
            int sj = __shfl(start_lane, j);
            int ej = __shfl(end_lane, j);
            int deg = ej - sj;
            for (int q = 64; q < deg; q++) {
                int i0 = csr_src[sj + q];
                uint2 v0 = base[(size_t)i0 * 64 + lane];
                a[j][0] += blo(v0.x); a[j][1] += bhi(v0.x);
                a[j][2] += blo(v0.y); a[j][3] += bhi(v0.y);
            }
        }
    }

    float4 b = ((const float4*)bias)[lane];
    #pragma unroll
    for (int j = 0; j < NPW; j++) {
        int n = n0 + j;
        if (j < nv && n < NN) {
            int cnt = __shfl(end_lane, j) - __shfl(start_lane, j);
            float scl = rsqrtf((float)(cnt > 1 ? cnt : 1));
            float r0 = a[j][0] * scl + b.x;
            float r1 = a[j][1] * scl + b.y;
            float r2 = a[j][2] * scl + b.z;
            float r3 = a[j][3] * scl + b.w;
            if (MODE == 0) {
                r0 = fmaxf(r0, 0.f); r1 = fmaxf(r1, 0.f);
                r2 = fmaxf(r2, 0.f); r3 = fmaxf(r3, 0.f);
                uint2 o;
                o.x = (uint_t)f2bf(r0) | ((uint_t)f2bf(r1) << 16);
                o.y = (uint_t)f2bf(r2) | ((uint_t)f2bf(r3) << 16);
                ((uint2*)outp)[(size_t)n * 64 + lane] = o;
            } else {
                float s1 = r0 + r1 + r2 + r3;
                #pragma unroll
                for (int off = 1; off < 64; off <<= 1) s1 += __shfl_xor(s1, off);
                float mu = s1 * (1.f / 256.f);
                float d0 = r0 - mu, d1 = r1 - mu, d2 = r2 - mu, d3 = r3 - mu;
                float s2 = d0 * d0 + d1 * d1 + d2 * d2 + d3 * d3;
                #pragma unroll
                for (int off = 1; off < 64; off <<= 1) s2 += __shfl_xor(s2, off);
                float rs = rsqrtf(s2 * (1.f / 256.f) + LN_EPS);
                float4 g  = ((const float4*)gamma)[lane];
                float4 be = ((const float4*)beta)[lane];
                float4 o;
                o.x = d0 * rs * g.x + be.x;
                o.y = d1 * rs * g.y + be.y;
                o.z = d2 * rs * g.z + be.z;
                o.w = d3 * rs * g.w + be.w;
                ((float4*)outp)[(size_t)n * 64 + lane] = o;
            }
        }
    }
}

extern "C" void kernel_launch(void* const* d_in, const int* in_sizes, int n_in,
                              void* d_out, int out_size, void* d_ws, size_t ws_size,
                              hipStream_t stream)
{
    const float* x     = (const float*)d_in[0];
    const float* W1    = (const float*)d_in[1];
    const float* b1    = (const float*)d_in[2];
    const float* W2    = (const float*)d_in[3];
    const float* b2    = (const float*)d_in[4];
    const float* gamma = (const float*)d_in[5];
    const float* beta  = (const float*)d_in[6];
    const int*   src   = (const int*)d_in[7];
    const int*   dst   = (const int*)d_in[8];
    float* out = (float*)d_out;

    // ws layout (~49 MB)
    uint_t*   dpart  = (uint_t*)d_ws;                        // EE uint     6.4MB
    ushort_t* msg    = (ushort_t*)(dpart + EE);              // MPAD*256   25.6MB
    int*      csr    = (int*)(msg + (size_t)MPAD * 256);     // EE          6.4MB
    int*      spart  = csr + EE;                             // EE          6.4MB
    int*      rp16   = spart + EE;                           // NB*FB+32    3.2MB
    int*      cntD   = rp16 + NB * FB + 32;
    int*      cntS   = cntD + NB * NBLK;
    int*      scanD  = cntS + NB * NBLK;
    int*      scanS  = scanD + NB * NBLK;
    int*      bbD    = scanS + NB * NBLK;                    // 320 (257 used)
    int*      bbS    = bbD + 320;                            // 320
    int*      degout = bbS + 320;                            // 50176
    ushort_t* Wt1    = (ushort_t*)(degout + NTOT);           // 65536 bf16
    ushort_t* Wt2    = Wt1 + 65536;                          // 65536 bf16

    ushort_t* h = (ushort_t*)d_out;   // layer-1 activation (bf16) in d_out

    radix_count  <<<NBLK, 256, 0, stream>>>(src, dst, cntD, cntS);
    radix_scan   <<<2, 256, 0, stream>>>(cntD, scanD, bbD, cntS, scanS, bbS);
    radix_scatter<<<NBLK, 256, 0, stream>>>(src, dst, scanD, scanS, dpart, spart);
    fine_dst     <<<NB, 256, 0, stream>>>(dpart, bbD, rp16, csr);
    fine_src     <<<NB, 256, 0, stream>>>(spart, bbS, degout);
    wconv2       <<<512, 256, 0, stream>>>(W1, W2, Wt1, Wt2);

    int ablocks = (NTOT + 4 * NPW - 1) / (4 * NPW);   // 965 (co-resident)
    gemm_mfma<0><<<MPAD / 64, 256, 0, stream>>>(x, Wt1, degout, msg);
    aggregate_v3<0><<<ablocks, 256, 0, stream>>>(msg, rp16, csr,
                                                 b1, nullptr, nullptr, h);
    gemm_mfma<1><<<MPAD / 64, 256, 0, stream>>>(h, Wt2, degout, msg);
    aggregate_v3<1><<<ablocks, 256, 0, stream>>>(msg, rp16, csr,
                                                 b2, gamma, beta, out);
}

// Round 12
// 424.791 us; speedup vs baseline: 1.5410x; 1.5410x over previous
//
#include <hip/hip_runtime.h>
#include <hip/hip_fp8.h>

#define NN 50000
#define EE 1600000
#define HD 256
#define MPAD 50048      // 391 * 128
#define LN_EPS 1e-5f

#define NB 256          // coarse buckets
#define BR 196          // node range per bucket (256*196 = 50176)
#define NTOT (NB * BR)  // 50176
#define NBLK 128        // radix count/scatter blocks
#define CH 12500        // edges per block
#define SL 16           // src slices (src>>12)
#define SSH 12
#define FB 3136         // fine bins = BR*SL
#define FBP 3328        // padded to 256*13
#define CF 13           // fine scan chunk per thread

typedef unsigned short ushort_t;
typedef unsigned int uint_t;
typedef unsigned char uchar_t;

using frag_ab = __attribute__((ext_vector_type(8))) short;   // 8 bf16
using frag_cd = __attribute__((ext_vector_type(4))) float;   // 4 f32

__device__ __forceinline__ ushort_t f2bf(float f) {
    uint_t u = __float_as_uint(f);
    uint_t r = (u + 0x7FFFu + ((u >> 16) & 1u)) >> 16;
    return (ushort_t)r;
}
__device__ __forceinline__ float blo(uint_t u) { return __uint_as_float(u << 16); }
__device__ __forceinline__ float bhi(uint_t u) { return __uint_as_float(u & 0xFFFF0000u); }

__device__ __forceinline__ uchar_t f2fp8(float f) {
    __hip_fp8_e4m3 q(f);
    return (uchar_t)q.__x;
}
__device__ __forceinline__ float fp8f(uint_t byte) {
    __hip_fp8_e4m3 t;
    t.__x = (__hip_fp8_storage_t)byte;
    return (float)t;
}

// ============ radix pass 1: coarse counts, per-wave sub-histograms ============
__global__ __launch_bounds__(256) void radix_count(
    const int* __restrict__ src, const int* __restrict__ dst,
    int* __restrict__ cntD, int* __restrict__ cntS)
{
    __shared__ int hD[4][NB], hS[4][NB];
    int t = threadIdx.x, blk = blockIdx.x, wv = t >> 6;
    #pragma unroll
    for (int w = 0; w < 4; w++) { hD[w][t] = 0; hS[w][t] = 0; }
    __syncthreads();
    for (int i = t; i < CH; i += 256) {
        int e = blk * CH + i;
        atomicAdd(&hD[wv][dst[e] / BR], 1);
        atomicAdd(&hS[wv][src[e] / BR], 1);
    }
    __syncthreads();
    cntD[t * NBLK + blk] = hD[0][t] + hD[1][t] + hD[2][t] + hD[3][t];
    cntS[t * NBLK + blk] = hS[0][t] + hS[1][t] + hS[2][t] + hS[3][t];
}

// ============ radix scan: exclusive scan of 32768 (bucket-major) ==============
__global__ __launch_bounds__(256) void radix_scan(
    const int* __restrict__ cntD, int* __restrict__ scanD, int* __restrict__ bbD,
    const int* __restrict__ cntS, int* __restrict__ scanS, int* __restrict__ bbS)
{
    const int* cnt = (blockIdx.x == 0) ? cntD : cntS;
    int* scn       = (blockIdx.x == 0) ? scanD : scanS;
    int* bb        = (blockIdx.x == 0) ? bbD : bbS;
    int t = threadIdx.x, lane = t & 63, wv = t >> 6;
    int base = t * NBLK;
    int s = 0;
    for (int j = 0; j < NBLK; j++) s += cnt[base + j];
    int sc = s;
    #pragma unroll
    for (int off = 1; off < 64; off <<= 1) {
        int nv = __shfl_up(sc, off);
        if (lane >= off) sc += nv;
    }
    __shared__ int wp[4];
    if (lane == 63) wp[wv] = sc;
    __syncthreads();
    int wb = 0;
    for (int w = 0; w < wv; w++) wb += wp[w];
    int run = wb + sc - s;
    bb[t] = run;
    for (int j = 0; j < NBLK; j++) { scn[base + j] = run; run += cnt[base + j]; }
    if (t == 255) bb[256] = run;    // total = EE
}

// ============ radix scatter: dst-partition (packed 4B) and src-partition ======
__global__ __launch_bounds__(256) void radix_scatter(
    const int* __restrict__ src, const int* __restrict__ dst,
    const int* __restrict__ scanD, const int* __restrict__ scanS,
    uint_t* __restrict__ dpart, int* __restrict__ spart)
{
    __shared__ int curD[NB], curS[NB];
    int t = threadIdx.x, blk = blockIdx.x;
    curD[t] = scanD[t * NBLK + blk];
    curS[t] = scanS[t * NBLK + blk];
    __syncthreads();
    for (int i = t; i < CH; i += 256) {
        int e = blk * CH + i;
        int sv = src[e], dv = dst[e];
        int bk = dv / BR;
        int ld = dv - bk * BR;                 // 0..195, 8 bits
        int pd = atomicAdd(&curD[bk], 1);
        dpart[pd] = (uint_t)sv | ((uint_t)ld << 16);   // sv fits 16 bits
        int ps = atomicAdd(&curS[sv / BR], 1);
        spart[ps] = sv;
    }
}

// ============ fine stage (dst): per-bucket CSR sorted by (dst, src-slice) =====
__global__ __launch_bounds__(256) void fine_dst(
    const uint_t* __restrict__ dpart, const int* __restrict__ bbD,
    int* __restrict__ rp16, int* __restrict__ csr_src)
{
    __shared__ int hist[FBP];
    __shared__ int cur[FBP];
    __shared__ int wp[4];
    int t = threadIdx.x, lane = t & 63, wv = t >> 6;
    int b = blockIdx.x;
    int bb = bbD[b];
    int cnt = bbD[b + 1] - bb;
    #pragma unroll
    for (int j = 0; j < CF; j++) hist[t * CF + j] = 0;
    __syncthreads();
    for (int i = t; i < cnt; i += 256) {
        uint_t p = dpart[bb + i];
        int sv = (int)(p & 0xFFFFu);
        int ld = (int)(p >> 16);
        atomicAdd(&hist[ld * SL + (sv >> SSH)], 1);
    }
    __syncthreads();
    int vals[CF];
    int s = 0;
    #pragma unroll
    for (int j = 0; j < CF; j++) { vals[j] = hist[t * CF + j]; s += vals[j]; }
    int sc = s;
    #pragma unroll
    for (int off = 1; off < 64; off <<= 1) {
        int nv = __shfl_up(sc, off);
        if (lane >= off) sc += nv;
    }
    if (lane == 63) wp[wv] = sc;
    __syncthreads();
    int wb = 0;
    for (int w = 0; w < wv; w++) wb += wp[w];
    int run = wb + sc - s;
    #pragma unroll
    for (int j = 0; j < CF; j++) {
        int bin = t * CF + j;
        cur[bin] = run;
        if (bin < FB) rp16[b * FB + bin] = bb + run;
        run += vals[j];
    }
    if (b == NB - 1 && t == 0) rp16[NB * FB] = bbD[NB];   // sentinel = EE
    __syncthreads();
    for (int i = t; i < cnt; i += 256) {
        uint_t p = dpart[bb + i];
        int sv = (int)(p & 0xFFFFu);
        int ld = (int)(p >> 16);
        int pos = bb + atomicAdd(&cur[ld * SL + (sv >> SSH)], 1);
        csr_src[pos] = sv;
    }
}

// ============ fine stage (src): per-bucket histogram -> deg_out ===============
__global__ __launch_bounds__(256) void fine_src(
    const int* __restrict__ spart, const int* __restrict__ bbS,
    int* __restrict__ deg_out)
{
    __shared__ int hist[NB];
    int t = threadIdx.x, b = blockIdx.x;
    hist[t] = 0;
    __syncthreads();
    int bb = bbS[b];
    int cnt = bbS[b + 1] - bb;
    int node0 = b * BR;
    for (int i = t; i < cnt; i += 256) atomicAdd(&hist[spart[bb + i] - node0], 1);
    __syncthreads();
    if (t < BR) deg_out[node0 + t] = hist[t];
}

// ---------------- W convert + transpose (both weights, one launch) ------------
__global__ void wconv2(const float* __restrict__ W1, const float* __restrict__ W2,
                       ushort_t* __restrict__ Wt1, ushort_t* __restrict__ Wt2) {
    int b = blockIdx.x;
    const float* W = (b < 256) ? W1 : W2;
    ushort_t* Wt   = (b < 256) ? Wt1 : Wt2;
    int g = (b & 255) * 256 + threadIdx.x;
    int k = g >> 8, n = g & 255;
    Wt[n * 256 + k] = f2bf(W[g]);
}

// ---------------- bf16 MFMA GEMM: BM=64, BN=256; OUT_FP8 selects epilogue -----
__device__ __forceinline__ int swz(int r, int kElem) {
    return ((r * 64 + kElem) * 2) ^ ((r & 7) << 4);
}

template <int A_BF16, int OUT_FP8>
__global__ __launch_bounds__(256) void gemm_mfma(
    const void* __restrict__ Aptr, const ushort_t* __restrict__ Wt,
    const int* __restrict__ deg, void* __restrict__ Yp)
{
    __shared__ __align__(16) ushort_t As[4096];    // 64 rows x 64 k (swizzled)
    __shared__ __align__(16) ushort_t Bs[16384];   // 256 cols x 64 k (swizzled)
    __shared__ float sS[64];

    int t = threadIdx.x;
    int lane = t & 63, wn = t >> 6;     // 4 waves, each owns 64x64 output
    int row0 = blockIdx.x * 64;

    if (t < 64) {
        int row = row0 + t;
        int dg = (row < NN) ? deg[row] : 1;
        sS[t] = rsqrtf((float)(dg > 1 ? dg : 1));
    }

    frag_cd acc[4][4];
    #pragma unroll
    for (int m = 0; m < 4; m++)
        #pragma unroll
        for (int n = 0; n < 4; n++) acc[m][n] = (frag_cd)(0.f);

    const float*    Af = (const float*)Aptr;
    const ushort_t* Ab = (const ushort_t*)Aptr;

    for (int k0 = 0; k0 < HD; k0 += 64) {
        __syncthreads();
        // stage A: 64x64 (4 iters)
        #pragma unroll
        for (int i = 0; i < 4; i++) {
            int flat = i * 256 + t;
            int r = flat >> 4;
            int k4 = (flat & 15) * 4;
            int row = row0 + r;
            ushort4 u;
            if constexpr (!A_BF16) {
                float4 v = make_float4(0.f, 0.f, 0.f, 0.f);
                if (row < NN) v = *(const float4*)&Af[(size_t)row * 256 + k0 + k4];
                u.x = f2bf(v.x); u.y = f2bf(v.y); u.z = f2bf(v.z); u.w = f2bf(v.w);
            } else {
                if (row < NN) u = *(const ushort4*)&Ab[(size_t)row * 256 + k0 + k4];
                else u = make_ushort4(0, 0, 0, 0);
            }
            *(ushort4*)((char*)As + swz(r, k4)) = u;
        }
        // stage B: 256x64 (16 iters) — Wt is L2-resident (128 KB)
        #pragma unroll
        for (int i = 0; i < 16; i++) {
            int flat = i * 256 + t;
            int nn = flat >> 4;
            int k4 = (flat & 15) * 4;
            ushort4 u = *(const ushort4*)&Wt[(size_t)nn * 256 + k0 + k4];
            *(ushort4*)((char*)Bs + swz(nn, k4)) = u;
        }
        __syncthreads();
        #pragma unroll
        for (int s = 0; s < 2; s++) {
            int kb = s * 32 + ((lane >> 4) * 8);
            frag_ab af[4], bfr[4];
            #pragma unroll
            for (int m = 0; m < 4; m++) {
                int r = m * 16 + (lane & 15);
                af[m] = *(const frag_ab*)((const char*)As + swz(r, kb));
            }
            #pragma unroll
            for (int n = 0; n < 4; n++) {
                int c = wn * 64 + n * 16 + (lane & 15);
                bfr[n] = *(const frag_ab*)((const char*)Bs + swz(c, kb));
            }
            #pragma unroll
            for (int m = 0; m < 4; m++)
                #pragma unroll
                for (int n = 0; n < 4; n++)
                    acc[m][n] = __builtin_amdgcn_mfma_f32_16x16x32_bf16(
                        af[m], bfr[n], acc[m][n], 0, 0, 0);
        }
    }

    // epilogue: row-scale, store fp8 or bf16
    #pragma unroll
    for (int m = 0; m < 4; m++) {
        int rl = m * 16 + ((lane >> 4) * 4);
        #pragma unroll
        for (int j = 0; j < 4; j++) {
            float sc = sS[rl + j];
            size_t grow = (size_t)(row0 + rl + j);
            #pragma unroll
            for (int n = 0; n < 4; n++) {
                int gcol = wn * 64 + n * 16 + (lane & 15);
                if constexpr (OUT_FP8) {
                    ((uchar_t*)Yp)[grow * 256 + gcol] = f2fp8(acc[m][n][j] * sc);
                } else {
                    ((ushort_t*)Yp)[grow * 256 + gcol] = f2bf(acc[m][n][j] * sc);
                }
            }
        }
    }
}

// ---------------- CSR gather aggregation, fp8 messages (layer 1) --------------
// out: h[bf16] = relu(sum * rsqrt(deg_in) + bias)
__global__ __launch_bounds__(256) void aggregate_fp8(
    const uint_t* __restrict__ msg, const int* __restrict__ rp16,
    const int* __restrict__ csr_src, const float* __restrict__ bias,
    void* __restrict__ outp)
{
    int wv = threadIdx.x >> 6, lane = threadIdx.x & 63;
    int n = blockIdx.x * 4 + wv;
    if (n >= NN) return;
    int start = rp16[n * SL];
    int end   = rp16[n * SL + SL];
    int cnt = end - start;
    float a0 = 0.f, a1 = 0.f, a2 = 0.f, a3 = 0.f;

    for (int c0 = 0; c0 < cnt; c0 += 64) {
        int nc = cnt - c0; if (nc > 64) nc = 64;
        int ss = csr_src[start + c0 + ((lane < nc) ? lane : 0)];
        int i = 0;
        for (; i + 16 <= nc; i += 16) {
            uint_t v[16];
            #pragma unroll
            for (int j = 0; j < 16; j++) {
                int idx = __shfl(ss, i + j);
                v[j] = msg[(size_t)idx * 64 + lane];
            }
            #pragma unroll
            for (int j = 0; j < 16; j++) {
                a0 += fp8f(v[j] & 0xFFu);         a1 += fp8f((v[j] >> 8) & 0xFFu);
                a2 += fp8f((v[j] >> 16) & 0xFFu); a3 += fp8f(v[j] >> 24);
            }
        }
        if (i + 8 <= nc) {
            uint_t v[8];
            #pragma unroll
            for (int j = 0; j < 8; j++) {
                int idx = __shfl(ss, i + j);
                v[j] = msg[(size_t)idx * 64 + lane];
            }
            #pragma unroll
            for (int j = 0; j < 8; j++) {
                a0 += fp8f(v[j] & 0xFFu);         a1 += fp8f((v[j] >> 8) & 0xFFu);
                a2 += fp8f((v[j] >> 16) & 0xFFu); a3 += fp8f(v[j] >> 24);
            }
            i += 8;
        }
        if (i + 4 <= nc) {
            uint_t v[4];
            #pragma unroll
            for (int j = 0; j < 4; j++) {
                int idx = __shfl(ss, i + j);
                v[j] = msg[(size_t)idx * 64 + lane];
            }
            #pragma unroll
            for (int j = 0; j < 4; j++) {
                a0 += fp8f(v[j] & 0xFFu);         a1 += fp8f((v[j] >> 8) & 0xFFu);
                a2 += fp8f((v[j] >> 16) & 0xFFu); a3 += fp8f(v[j] >> 24);
            }
            i += 4;
        }
        for (; i < nc; i++) {
            int idx = __shfl(ss, i);
            uint_t v = msg[(size_t)idx * 64 + lane];
            a0 += fp8f(v & 0xFFu);         a1 += fp8f((v >> 8) & 0xFFu);
            a2 += fp8f((v >> 16) & 0xFFu); a3 += fp8f(v >> 24);
        }
    }

    float scl = rsqrtf((float)(cnt > 1 ? cnt : 1));
    float4 b = ((const float4*)bias)[lane];
    float r0 = fmaxf(a0 * scl + b.x, 0.f);
    float r1 = fmaxf(a1 * scl + b.y, 0.f);
    float r2 = fmaxf(a2 * scl + b.z, 0.f);
    float r3 = fmaxf(a3 * scl + b.w, 0.f);
    uint2 o;
    o.x = (uint_t)f2bf(r0) | ((uint_t)f2bf(r1) << 16);
    o.y = (uint_t)f2bf(r2) | ((uint_t)f2bf(r3) << 16);
    ((uint2*)outp)[(size_t)n * 64 + lane] = o;
}

// ---------------- CSR gather aggregation, bf16 messages (layer 2 + LN) --------
__global__ __launch_bounds__(256) void aggregate_bf16(
    const ushort_t* __restrict__ msg, const int* __restrict__ rp16,
    const int* __restrict__ csr_src, const float* __restrict__ bias,
    const float* __restrict__ gamma, const float* __restrict__ beta,
    float* __restrict__ outp)
{
    int wv = threadIdx.x >> 6, lane = threadIdx.x & 63;
    int n = blockIdx.x * 4 + wv;
    if (n >= NN) return;
    int start = rp16[n * SL];
    int end   = rp16[n * SL + SL];
    int cnt = end - start;
    float a0 = 0.f, a1 = 0.f, a2 = 0.f, a3 = 0.f;
    const uint2* base = (const uint2*)msg;

    for (int c0 = 0; c0 < cnt; c0 += 64) {
        int nc = cnt - c0; if (nc > 64) nc = 64;
        int ss = csr_src[start + c0 + ((lane < nc) ? lane : 0)];
        int i = 0;
        for (; i + 16 <= nc; i += 16) {
            uint2 v[16];
            #pragma unroll
            for (int j = 0; j < 16; j++) {
                int idx = __shfl(ss, i + j);
                v[j] = base[(size_t)idx * 64 + lane];
            }
            #pragma unroll
            for (int j = 0; j < 16; j++) {
                a0 += blo(v[j].x); a1 += bhi(v[j].x);
                a2 += blo(v[j].y); a3 += bhi(v[j].y);
            }
        }
        if (i + 8 <= nc) {
            uint2 v[8];
            #pragma unroll
            for (int j = 0; j < 8; j++) {
                int idx = __shfl(ss, i + j);
                v[j] = base[(size_t)idx * 64 + lane];
            }
            #pragma unroll
            for (int j = 0; j < 8; j++) {
                a0 += blo(v[j].x); a1 += bhi(v[j].x);
                a2 += blo(v[j].y); a3 += bhi(v[j].y);
            }
            i += 8;
        }
        if (i + 4 <= nc) {
            uint2 v[4];
            #pragma unroll
            for (int j = 0; j < 4; j++) {
                int idx = __shfl(ss, i + j);
                v[j] = base[(size_t)idx * 64 + lane];
            }
            #pragma unroll
            for (int j = 0; j < 4; j++) {
                a0 += blo(v[j].x); a1 += bhi(v[j].x);
                a2 += blo(v[j].y); a3 += bhi(v[j].y);
            }
            i += 4;
        }
        for (; i < nc; i++) {
            int idx = __shfl(ss, i);
            uint2 v = base[(size_t)idx * 64 + lane];
            a0 += blo(v.x); a1 += bhi(v.x); a2 += blo(v.y); a3 += bhi(v.y);
        }
    }

    float scl = rsqrtf((float)(cnt > 1 ? cnt : 1));
    float4 b = ((const float4*)bias)[lane];
    float r0 = a0 * scl + b.x;
    float r1 = a1 * scl + b.y;
    float r2 = a2 * scl + b.z;
    float r3 = a3 * scl + b.w;

    float s1 = r0 + r1 + r2 + r3;
    #pragma unroll
    for (int off = 1; off < 64; off <<= 1) s1 += __shfl_xor(s1, off);
    float mu = s1 * (1.f / 256.f);
    float d0 = r0 - mu, d1 = r1 - mu, d2 = r2 - mu, d3 = r3 - mu;
    float s2 = d0 * d0 + d1 * d1 + d2 * d2 + d3 * d3;
    #pragma unroll
    for (int off = 1; off < 64; off <<= 1) s2 += __shfl_xor(s2, off);
    float rs = rsqrtf(s2 * (1.f / 256.f) + LN_EPS);
    float4 g  = ((const float4*)gamma)[lane];
    float4 be = ((const float4*)beta)[lane];
    float4 o;
    o.x = d0 * rs * g.x + be.x;
    o.y = d1 * rs * g.y + be.y;
    o.z = d2 * rs * g.z + be.z;
    o.w = d3 * rs * g.w + be.w;
    ((float4*)&outp[(size_t)n * 256])[lane] = o;
}

extern "C" void kernel_launch(void* const* d_in, const int* in_sizes, int n_in,
                              void* d_out, int out_size, void* d_ws, size_t ws_size,
                              hipStream_t stream)
{
    const float* x     = (const float*)d_in[0];
    const float* W1    = (const float*)d_in[1];
    const float* b1    = (const float*)d_in[2];
    const float* W2    = (const float*)d_in[3];
    const float* b2    = (const float*)d_in[4];
    const float* gamma = (const float*)d_in[5];
    const float* beta  = (const float*)d_in[6];
    const int*   src   = (const int*)d_in[7];
    const int*   dst   = (const int*)d_in[8];
    float* out = (float*)d_out;

    // ws layout (~49 MB). msg8 aliases dpart+spart (dead after setup).
    char* base = (char*)d_ws;
    uchar_t*  msg8   = (uchar_t*)base;                       // [0, 12,812,288) fp8 msgs
    uint_t*   dpart  = (uint_t*)base;                        // setup only
    int*      spart  = (int*)(base + 6400000);               // setup only
    int*      csr    = (int*)(base + 12812288);              // EE          6.4MB
    int*      rp16   = (int*)(base + 19212288);              // NB*FB+32    3.2MB
    int*      cntD   = (int*)(base + 22423680);
    int*      cntS   = cntD + NB * NBLK;
    int*      scanD  = cntS + NB * NBLK;
    int*      scanS  = scanD + NB * NBLK;
    int*      bbD    = scanS + NB * NBLK;                    // 320 (257 used)
    int*      bbS    = bbD + 320;
    int*      degout = bbS + 320;                            // 50176
    ushort_t* Wt1    = (ushort_t*)(degout + NTOT);           // 65536 bf16
    ushort_t* Wt2    = Wt1 + 65536;
    ushort_t* msg16  = Wt2 + 65536;                          // MPAD*256 bf16 25.6MB

    ushort_t* h = (ushort_t*)d_out;   // layer-1 activation (bf16) in d_out

    radix_count  <<<NBLK, 256, 0, stream>>>(src, dst, cntD, cntS);
    radix_scan   <<<2, 256, 0, stream>>>(cntD, scanD, bbD, cntS, scanS, bbS);
    radix_scatter<<<NBLK, 256, 0, stream>>>(src, dst, scanD, scanS, dpart, spart);
    fine_dst     <<<NB, 256, 0, stream>>>(dpart, bbD, rp16, csr);
    fine_src     <<<NB, 256, 0, stream>>>(spart, bbS, degout);
    wconv2       <<<512, 256, 0, stream>>>(W1, W2, Wt1, Wt2);

    // layer 1: fp8 messages (msg8 overwrites dpart/spart region — setup done)
    gemm_mfma<0, 1><<<MPAD / 64, 256, 0, stream>>>(x, Wt1, degout, msg8);
    aggregate_fp8<<<(NN + 3) / 4, 256, 0, stream>>>((const uint_t*)msg8, rp16, csr,
                                                    b1, h);
    // layer 2: bf16 messages
    gemm_mfma<1, 0><<<MPAD / 64, 256, 0, stream>>>(h, Wt2, degout, msg16);
    aggregate_bf16<<<(NN + 3) / 4, 256, 0, stream>>>(msg16, rp16, csr,
                                                     b2, gamma, beta, out);
}